// Round 3
// baseline (432.096 us; speedup 1.0000x reference)
//
#include <hip/hip_runtime.h>

// HorizontalWidthTokenPyramid: x[n,c,s,16,16] f32 -> out[n,c,s,31,4] f32
// v3: shuffle-free. lane = s*4 + g (s = slice-in-wave 0..15, g = token 0..3).
// Each lane owns one token column of one slice: rows 0..15, cols 4g..4g+3,
// i.e. 16 float4 loads. The whole height pyramid (spans 1,2,4,8,16 with
// sum & max) is computed in registers -- zero cross-lane ops, every lane
// does unique work. Per load instr: 16 slices x 64B contiguous = 1KB fully
// coalesced. Stores are plain dwords (4 consecutive floats/slice per instr);
// L2 write-combines since a wave covers 16 contiguous slices' outputs.

__device__ __forceinline__ float4 add4(float4 a, float4 b) {
    return make_float4(a.x + b.x, a.y + b.y, a.z + b.z, a.w + b.w);
}
__device__ __forceinline__ float4 max4(float4 a, float4 b) {
    return make_float4(fmaxf(a.x, b.x), fmaxf(a.y, b.y),
                       fmaxf(a.z, b.z), fmaxf(a.w, b.w));
}
__device__ __forceinline__ float hsum(float4 a) {
    return (a.x + a.y) + (a.z + a.w);
}
__device__ __forceinline__ float hmax(float4 a) {
    return fmaxf(fmaxf(a.x, a.y), fmaxf(a.z, a.w));
}
// token value for a bin: z_c = sum_c*inv_span + max_c; 0.25*sum_c(z) + max_c(z)
__device__ __forceinline__ float token_val(float4 s, float4 m, float inv_span) {
    float4 z = make_float4(fmaf(s.x, inv_span, m.x), fmaf(s.y, inv_span, m.y),
                           fmaf(s.z, inv_span, m.z), fmaf(s.w, inv_span, m.w));
    return fmaf(hsum(z), 0.25f, hmax(z));
}

__global__ __launch_bounds__(256) void hwtp_kernel(const float* __restrict__ x,
                                                   float* __restrict__ out,
                                                   int num_slices) {
    const int lane = threadIdx.x & 63;
    const int wave = (blockIdx.x * blockDim.x + threadIdx.x) >> 6;
    const int s    = lane >> 2;           // slice-in-wave 0..15
    const int g    = lane & 3;            // width token 0..3
    const int slice = wave * 16 + s;
    if (slice >= num_slices) return;

    const float4* __restrict__ xv = reinterpret_cast<const float4*>(x);
    const size_t base = (size_t)slice * 64 + g;   // float4 idx: slice*64 + r*4 + g

    float4 row[16];
#pragma unroll
    for (int r = 0; r < 16; ++r)
        row[r] = xv[base + (size_t)(r * 4)];

    float* __restrict__ o = out + (size_t)slice * 124;

    float4 s4, m4, s8, m8, s16, m16;

#pragma unroll
    for (int j = 0; j < 8; ++j) {                 // row pairs (2j, 2j+1)
        const float4 a = row[2 * j];
        const float4 b = row[2 * j + 1];

        // ---- b=16 (span 1): z = 2x -> val = 0.5*hsum + 2*hmax ----
        o[(2 * j) * 4 + g]     = fmaf(hsum(a), 0.5f, 2.0f * hmax(a));
        o[(2 * j + 1) * 4 + g] = fmaf(hsum(b), 0.5f, 2.0f * hmax(b));

        // ---- b=8 (span 2): bin j ----
        const float4 ps = add4(a, b);
        const float4 pm = max4(a, b);
        o[64 + j * 4 + g] = token_val(ps, pm, 0.5f);

        // ---- b=4 (span 4): bin j>>1 ----
        if ((j & 1) == 0) { s4 = ps; m4 = pm; }
        else {
            s4 = add4(s4, ps); m4 = max4(m4, pm);
            o[96 + (j >> 1) * 4 + g] = token_val(s4, m4, 0.25f);

            // ---- b=2 (span 8): bin j>>2 ----
            if ((j & 3) == 1) { s8 = s4; m8 = m4; }
            else {
                s8 = add4(s8, s4); m8 = max4(m8, m4);
                o[112 + (j >> 2) * 4 + g] = token_val(s8, m8, 0.125f);

                // ---- b=1 (span 16) ----
                if (j == 3) { s16 = s8; m16 = m8; }
                else {  // j == 7
                    s16 = add4(s16, s8); m16 = max4(m16, m8);
                    o[120 + g] = token_val(s16, m16, 0.0625f);
                }
            }
        }
    }
}

extern "C" void kernel_launch(void* const* d_in, const int* in_sizes, int n_in,
                              void* d_out, int out_size, void* d_ws, size_t ws_size,
                              hipStream_t stream) {
    const float* x = (const float*)d_in[0];
    float* out = (float*)d_out;

    const int num_slices = in_sizes[0] / 256;     // n*c*s, 256 floats/slice

    // one-shot: 16 slices per wave, 4 waves per block
    const int block = 256;
    const int slices_per_block = 64;
    const int grid = (num_slices + slices_per_block - 1) / slices_per_block;

    hwtp_kernel<<<grid, block, 0, stream>>>(x, out, num_slices);
}